// Round 1
// baseline (696.466 us; speedup 1.0000x reference)
//
#include <hip/hip_runtime.h>
#include <hip/hip_bf16.h>

#define B_ 4
#define S_ 2048
#define D_ 1024
#define H_ 16
#define M_ 8192   // B_*S_

typedef __attribute__((ext_vector_type(8))) _Float16 h8;
typedef __attribute__((ext_vector_type(8))) short    s8;
typedef __attribute__((ext_vector_type(4))) float    f4;

#define AS1(p) ((const __attribute__((address_space(1))) void*)(p))
#define AS3(p) ((__attribute__((address_space(3))) void*)(p))

__device__ __forceinline__ f4 mfma16(h8 a, h8 b, f4 c) {
  return __builtin_amdgcn_mfma_f32_16x16x32_f16(a, b, c, 0, 0, 0);
}

// ---------------- cast f32 -> f16 (q,k,v,Wq,Wk,Wv,Wo) ----------------
struct CastArgs {
  const float* src[7];
  _Float16*    dst[7];
  int cum[8];   // cumulative 8-element chunk counts
};

__global__ __launch_bounds__(256) void cast_kernel(CastArgs a) {
  int idx = blockIdx.x * 256 + threadIdx.x;
  if (idx >= a.cum[7]) return;
  int seg = 0;
#pragma unroll
  for (int s = 1; s < 7; ++s) seg += (idx >= a.cum[s]) ? 1 : 0;
  size_t off = (size_t)(idx - a.cum[seg]) * 8;
  const float4* sp = (const float4*)(a.src[seg] + off);
  float4 u = sp[0], v = sp[1];
  union { _Float16 h[8]; h8 v8; } o;
  o.h[0] = (_Float16)u.x; o.h[1] = (_Float16)u.y;
  o.h[2] = (_Float16)u.z; o.h[3] = (_Float16)u.w;
  o.h[4] = (_Float16)v.x; o.h[5] = (_Float16)v.y;
  o.h[6] = (_Float16)v.z; o.h[7] = (_Float16)v.w;
  *(h8*)(a.dst[seg] + off) = o.v8;
}

// ---------------- GEMM: C[M][1024] = (A[M][1024] @ Bt[1024][1024]^T + bias) * scale
// Bt is N-major, K-contiguous (== torch Linear weight layout), m97-style structure.
template<bool F32OUT>
__global__ __launch_bounds__(256, 3) void gemm_bt(
    const _Float16* __restrict__ A,
    const _Float16* __restrict__ Bt,
    const float*    __restrict__ bias,
    void*           __restrict__ Cout,
    float scale)
{
  __shared__ __align__(16) _Float16 Alds[128 * 64];
  __shared__ __align__(16) _Float16 Blds[128 * 64];
  const int t = threadIdx.x;
  const int lane = t & 63, w = t >> 6;
  const int wm = w >> 1, wn = w & 1;             // 2x2 wave grid, 64x64 each
  const int m0 = blockIdx.x * 128, n0 = blockIdx.y * 128;
  const int ll = lane & 15, lg = lane >> 4;
  f4 acc[4][4] = {};

  for (int kt = 0; kt < 1024; kt += 64) {
    __syncthreads();                              // protect LDS reuse
    // stage 128x64 A and B tiles; global source pre-swizzled so linear LDS
    // holds chunk (g ^ (row&7)) -> conflict-free ds_read_b128 later
#pragma unroll
    for (int i = 0; i < 4; ++i) {
      int slot = i * 256 + t;
      int r = slot >> 3;
      int gs = ((slot & 7) ^ (r & 7)) * 8;
      __builtin_amdgcn_global_load_lds(AS1(A  + (size_t)(m0 + r) * 1024 + kt + gs),
                                       AS3((char*)Alds + (i * 256 + w * 64) * 16), 16, 0, 0);
      __builtin_amdgcn_global_load_lds(AS1(Bt + (size_t)(n0 + r) * 1024 + kt + gs),
                                       AS3((char*)Blds + (i * 256 + w * 64) * 16), 16, 0, 0);
    }
    __syncthreads();                              // compiler drains vmcnt before barrier
#pragma unroll
    for (int ks = 0; ks < 2; ++ks) {
      h8 af[4], bf[4];
#pragma unroll
      for (int im = 0; im < 4; ++im) {
        int R = wm * 64 + im * 16 + ll;
        af[im] = *(const h8*)((const char*)Alds + R * 128 + (((ks * 4 + lg) ^ (R & 7)) << 4));
      }
#pragma unroll
      for (int in = 0; in < 4; ++in) {
        int R = wn * 64 + in * 16 + ll;
        bf[in] = *(const h8*)((const char*)Blds + R * 128 + (((ks * 4 + lg) ^ (R & 7)) << 4));
      }
#pragma unroll
      for (int im = 0; im < 4; ++im)
#pragma unroll
        for (int in = 0; in < 4; ++in)
          acc[im][in] = mfma16(af[im], bf[in], acc[im][in]);
    }
  }
  // epilogue: C-layout col = lane&15, row = (lane>>4)*4 + reg  [m89-verified]
#pragma unroll
  for (int im = 0; im < 4; ++im)
#pragma unroll
    for (int in = 0; in < 4; ++in) {
      int col = n0 + wn * 64 + in * 16 + ll;
      float bv = bias[col];
#pragma unroll
      for (int r = 0; r < 4; ++r) {
        int row = m0 + wm * 64 + im * 16 + lg * 4 + r;
        float vv = (acc[im][in][r] + bv) * scale;
        if constexpr (F32OUT) ((float*)Cout)[(size_t)row * 1024 + col] = vv;
        else ((_Float16*)Cout)[(size_t)row * 1024 + col] = (_Float16)vv;
      }
    }
}

// ---------------- V transpose: Vp[b*S+s][h*64+hd] -> Vt[(b*16+h)*64+hd][s] ----------------
__global__ __launch_bounds__(256) void transpose_v(
    const _Float16* __restrict__ Vp, _Float16* __restrict__ Vt)
{
  __shared__ __align__(16) short tile[64][72];    // +8 pad
  const int blk = blockIdx.x;
  const int b = blk >> 9, h = (blk >> 5) & 15, st = blk & 31;
  const int s0 = st * 64, t = threadIdx.x;
#pragma unroll
  for (int it = 0; it < 2; ++it) {
    int slot = it * 256 + t;
    int r = slot >> 3, c = slot & 7;
    s8 v = *(const s8*)(Vp + (size_t)(b * S_ + s0 + r) * D_ + h * 64 + c * 8);
    *(s8*)&tile[r][c * 8] = v;
  }
  __syncthreads();
#pragma unroll
  for (int it = 0; it < 2; ++it) {
    int slot = it * 256 + t;
    int hd = slot >> 3, c = slot & 7;
    union { short hh[8]; s8 v8; } o;
#pragma unroll
    for (int e = 0; e < 8; ++e) o.hh[e] = tile[c * 8 + e][hd];
    *(s8*)(Vt + (size_t)((b * 16 + h) * 64 + hd) * S_ + s0 + c * 8) = o.v8;
  }
}

// ---------------- fused flash attention ----------------
// grid: 512 = b(4) x 128 q-tiles of 16 rows. block: 1024 = 16 waves = 16 heads.
// Per k-tile (64): coop bias tile (shared by all heads) -> S=QK^T (MFMA) -> +bias
// -> online softmax -> P(f16) to swizzled LDS -> O^T += V^T . P^T (MFMA).
__global__ __launch_bounds__(1024, 1) void attn_kernel(
    const _Float16* __restrict__ Qp,   // [8192][1024], pre-scaled by 1/8
    const _Float16* __restrict__ Kp,   // [8192][1024]
    const _Float16* __restrict__ Vt,   // [(b*16+h)*64+hd][2048]
    const float*    __restrict__ td,   // [4][2048][2048]
    const int*      __restrict__ mask, // [4][2048][2048]
    const float*    __restrict__ gptr,
    _Float16*       __restrict__ Oa)   // [8192][1024]
{
  __shared__ float bias_lds[2][16][68];            // double-buffered, padded
  __shared__ __align__(16) short P_lds[16][1024];  // per-wave 16x64 f16, XOR-swizzled
  __shared__ float red[16][16];                    // per-wave broadcast scratch
  const int t = threadIdx.x;
  const int lane = t & 63, w = t >> 6;             // w = head
  const int ll = lane & 15, lg = lane >> 4;
  const int b = blockIdx.x >> 7;
  const int q0 = (blockIdx.x & 127) * 16;
  const float gamma = gptr[0];

  // Q a-frags hoisted (already scaled by 1/8 in projection)
  const size_t qrow = (size_t)(b * S_ + q0 + ll) * D_ + w * 64;
  h8 qf0 = *(const h8*)(Qp + qrow + lg * 8);
  h8 qf1 = *(const h8*)(Qp + qrow + 32 + lg * 8);

  float m[4], lsum[4];
#pragma unroll
  for (int r = 0; r < 4; ++r) { m[r] = -1e30f; lsum[r] = 0.f; }
  f4 accO[4] = {};                                 // O^T[d= df*16+lg*4+r][i= ll]

  const int bi = t >> 6, bj = t & 63;
  char* pbase = (char*)&P_lds[w][0];

  for (int kt = 0; kt < S_; kt += 64) {
    const int buf = (kt >> 6) & 1;
    {
      size_t off = ((size_t)b * S_ + (q0 + bi)) * S_ + kt + bj;
      float tv = td[off];
      int mk = mask[off];
      bias_lds[buf][bi][bj] = mk ? __expf(-gamma * tv) : -1e9f;
    }
    __syncthreads();

    // S-tile [16 q][64 k]
    f4 accS[4] = {};
#pragma unroll
    for (int jf = 0; jf < 4; ++jf) {
      const size_t krow = (size_t)(b * S_ + kt + jf * 16 + ll) * D_ + w * 64;
      h8 kf0 = *(const h8*)(Kp + krow + lg * 8);
      h8 kf1 = *(const h8*)(Kp + krow + 32 + lg * 8);
      accS[jf] = mfma16(qf0, kf0, accS[jf]);
      accS[jf] = mfma16(qf1, kf1, accS[jf]);
    }
    // + bias (masked entries are -1e9 -> score-1e9 == -1e9 in f32)
#pragma unroll
    for (int jf = 0; jf < 4; ++jf)
#pragma unroll
      for (int r = 0; r < 4; ++r)
        accS[jf][r] += bias_lds[buf][lg * 4 + r][ll + jf * 16];

    // online softmax; row i = lg*4+r, cols across ll and jf
    float tm[4], esc[4], ts[4];
#pragma unroll
    for (int r = 0; r < 4; ++r)
      tm[r] = fmaxf(fmaxf(accS[0][r], accS[1][r]), fmaxf(accS[2][r], accS[3][r]));
#pragma unroll
    for (int d = 1; d < 16; d <<= 1)
#pragma unroll
      for (int r = 0; r < 4; ++r)
        tm[r] = fmaxf(tm[r], __shfl_xor(tm[r], d));
#pragma unroll
    for (int r = 0; r < 4; ++r) {
      float mn = fmaxf(m[r], tm[r]);
      esc[r] = __expf(m[r] - mn);
      m[r] = mn;
      ts[r] = 0.f;
    }
    // P = exp(S-m), write f16 into swizzled LDS
#pragma unroll
    for (int jf = 0; jf < 4; ++jf)
#pragma unroll
      for (int r = 0; r < 4; ++r) {
        float p = __expf(accS[jf][r] - m[r]);
        ts[r] += p;
        int i = lg * 4 + r, j = ll + jf * 16;
        *(_Float16*)(pbase + i * 128 + ((2 * j) ^ ((i & 7) << 4))) = (_Float16)p;
      }
#pragma unroll
    for (int d = 1; d < 16; d <<= 1)
#pragma unroll
      for (int r = 0; r < 4; ++r)
        ts[r] += __shfl_xor(ts[r], d);
#pragma unroll
    for (int r = 0; r < 4; ++r)
      lsum[r] = lsum[r] * esc[r] + ts[r];

    // broadcast rescale factor to O^T layout (i = ll)
    if (ll == 0) {
#pragma unroll
      for (int r = 0; r < 4; ++r) red[w][lg * 4 + r] = esc[r];
    }
    asm volatile("s_waitcnt lgkmcnt(0)" ::: "memory");
    float ef = red[w][ll];
#pragma unroll
    for (int df = 0; df < 4; ++df)
#pragma unroll
      for (int r = 0; r < 4; ++r)
        accO[df][r] *= ef;

    // O^T += V^T . P^T  (both operands K-contiguous)
#pragma unroll
    for (int ks = 0; ks < 2; ++ks) {
      h8 pf = *(const h8*)(pbase + ll * 128 + ((ks * 64 + lg * 16) ^ ((ll & 7) << 4)));
#pragma unroll
      for (int df = 0; df < 4; ++df) {
        h8 vf = *(const h8*)(Vt + (size_t)((b * 16 + w) * 64 + df * 16 + ll) * S_ + kt + ks * 32 + lg * 8);
        accO[df] = mfma16(vf, pf, accO[df]);
      }
    }
  }

  // finalize: divide by row-sum, store O (scattered u16 — once per wg, cheap)
  if (ll == 0) {
#pragma unroll
    for (int r = 0; r < 4; ++r) red[w][lg * 4 + r] = lsum[r];
  }
  asm volatile("s_waitcnt lgkmcnt(0)" ::: "memory");
  float linv = 1.0f / red[w][ll];
#pragma unroll
  for (int df = 0; df < 4; ++df)
#pragma unroll
    for (int r = 0; r < 4; ++r) {
      size_t orow = (size_t)(b * S_ + q0 + ll) * D_ + w * 64 + df * 16 + lg * 4 + r;
      Oa[orow] = (_Float16)(accO[df][r] * linv);
    }
}

// ---------------- launcher ----------------
extern "C" void kernel_launch(void* const* d_in, const int* in_sizes, int n_in,
                              void* d_out, int out_size, void* d_ws, size_t ws_size,
                              hipStream_t stream) {
  const float* q    = (const float*)d_in[0];
  const float* k    = (const float*)d_in[1];
  const float* v    = (const float*)d_in[2];
  const float* td   = (const float*)d_in[3];
  const int*   mask = (const int*)d_in[4];
  const float* Wq   = (const float*)d_in[5];
  const float* bq   = (const float*)d_in[6];
  const float* Wk   = (const float*)d_in[7];
  const float* bk   = (const float*)d_in[8];
  const float* Wv   = (const float*)d_in[9];
  const float* bv   = (const float*)d_in[10];
  const float* Wo   = (const float*)d_in[11];
  const float* bo   = (const float*)d_in[12];
  const float* gm   = (const float*)d_in[13];

  const size_t MD = (size_t)M_ * D_;      // 8388608
  const size_t WW = (size_t)D_ * D_;      // 1048576
  if (ws_size < (8 * MD + 4 * WW) * sizeof(_Float16)) return;

  _Float16* base = (_Float16*)d_ws;
  _Float16* qh = base;
  _Float16* kh = qh + MD;
  _Float16* vh = kh + MD;
  _Float16* wq = vh + MD;
  _Float16* wk = wq + WW;
  _Float16* wv = wk + WW;
  _Float16* wo = wv + WW;
  _Float16* Qp = wo + WW;
  _Float16* Kp = Qp + MD;
  _Float16* Vp = Kp + MD;
  _Float16* Vt = Vp + MD;
  _Float16* Oa = Vt + MD;

  CastArgs ca;
  ca.src[0] = q;  ca.src[1] = k;  ca.src[2] = v;
  ca.src[3] = Wq; ca.src[4] = Wk; ca.src[5] = Wv; ca.src[6] = Wo;
  ca.dst[0] = qh; ca.dst[1] = kh; ca.dst[2] = vh;
  ca.dst[3] = wq; ca.dst[4] = wk; ca.dst[5] = wv; ca.dst[6] = wo;
  int sizes[7] = {(int)(MD / 8), (int)(MD / 8), (int)(MD / 8),
                  (int)(WW / 8), (int)(WW / 8), (int)(WW / 8), (int)(WW / 8)};
  int c = 0; ca.cum[0] = 0;
  for (int i = 0; i < 7; ++i) { c += sizes[i]; ca.cum[i + 1] = c; }
  cast_kernel<<<(c + 255) / 256, 256, 0, stream>>>(ca);

  dim3 gg(64, 8);
  gemm_bt<false><<<gg, 256, 0, stream>>>(qh, wq, bq, Qp, 0.125f);  // 1/sqrt(HD) folded in
  gemm_bt<false><<<gg, 256, 0, stream>>>(kh, wk, bk, Kp, 1.0f);
  gemm_bt<false><<<gg, 256, 0, stream>>>(vh, wv, bv, Vp, 1.0f);
  transpose_v<<<2048, 256, 0, stream>>>(Vp, Vt);
  attn_kernel<<<512, 1024, 0, stream>>>(Qp, Kp, Vt, td, mask, gm, Oa);
  gemm_bt<true><<<gg, 256, 0, stream>>>(Oa, wo, bo, d_out, 1.0f);
}